// Round 1
// baseline (1320.042 us; speedup 1.0000x reference)
//
#include <hip/hip_runtime.h>
#include <float.h>
#include <math.h>

#define BATCH 8
#define NPTS  2048
#define KNN   20
#define BN    (BATCH*NPTS)
#define SLOPE 0.2f
#define BNEPS 1e-5f

// ---------------- xx: per-point squared norm ----------------
__global__ void xx_kernel(const float* __restrict__ x, float* __restrict__ xx, int C) {
    int p = blockIdx.x * 256 + threadIdx.x;           // p in [0, BN)
    int b = p >> 11, n = p & (NPTS - 1);
    const float* xb = x + (size_t)b * C * NPTS;
    float s = 0.f;
    for (int c = 0; c < C; ++c) { float v = xb[(size_t)c * NPTS + n]; s = fmaf(v, v, s); }
    xx[p] = s;
}

// ---------------- kNN: one block per point row ----------------
__global__ __launch_bounds__(256) void knn_kernel(const float* __restrict__ x,
                                                  const float* __restrict__ xx,
                                                  int* __restrict__ idx, int C) {
    int p = blockIdx.x;
    int b = p >> 11, n = p & (NPTS - 1);
    const float* xb = x + (size_t)b * C * NPTS;
    __shared__ float dist[NPTS];
    __shared__ float ctr[64];
    __shared__ float redv[4];
    __shared__ int   redi[4];
    int t = threadIdx.x;
    if (t < C) ctr[t] = xb[(size_t)t * NPTS + n];
    __syncthreads();
    float xxn = xx[p];

    float acc[NPTS / 256];
#pragma unroll
    for (int mm = 0; mm < NPTS / 256; ++mm) acc[mm] = 0.f;
    for (int c = 0; c < C; ++c) {
        float cc = ctr[c];
        const float* row = xb + (size_t)c * NPTS + t;
#pragma unroll
        for (int mm = 0; mm < NPTS / 256; ++mm)
            acc[mm] = fmaf(cc, row[mm * 256], acc[mm]);
    }
    const float* xxb = xx + b * NPTS + t;
#pragma unroll
    for (int mm = 0; mm < NPTS / 256; ++mm)
        dist[t + mm * 256] = xxn - 2.f * acc[mm] + xxb[mm * 256];
    __syncthreads();

    int lane = t & 63, w = t >> 6;
    for (int r = 0; r < KNN; ++r) {
        float bv = FLT_MAX; int bi = 0x7fffffff;
#pragma unroll
        for (int mm = 0; mm < NPTS / 256; ++mm) {
            int m = t + mm * 256;
            float v = dist[m];
            if (v < bv || (v == bv && m < bi)) { bv = v; bi = m; }
        }
#pragma unroll
        for (int off = 1; off < 64; off <<= 1) {
            float ov = __shfl_xor(bv, off);
            int   oi = __shfl_xor(bi, off);
            if (ov < bv || (ov == bv && oi < bi)) { bv = ov; bi = oi; }
        }
        if (lane == 0) { redv[w] = bv; redi[w] = bi; }
        __syncthreads();
        if (t == 0) {
#pragma unroll
            for (int k = 1; k < 4; ++k)
                if (redv[k] < bv || (redv[k] == bv && redi[k] < bi)) { bv = redv[k]; bi = redi[k]; }
            idx[(size_t)p * KNN + r] = bi;
            dist[bi] = FLT_MAX;
        }
        __syncthreads();
    }
}

// ---------------- projection: y = x@Wtop, z = x@(Wbot-Wtop) ----------------
__global__ void proj_kernel(const float* __restrict__ x, const float* __restrict__ W,
                            float* __restrict__ y, float* __restrict__ z, int C, int Cout) {
    int p = blockIdx.x;
    int b = p >> 11, n = p & (NPTS - 1);
    int j = threadIdx.x;                      // j < Cout
    __shared__ float xc[64];
    if (j < C) xc[j] = x[(size_t)b * C * NPTS + (size_t)j * NPTS + n];
    __syncthreads();
    float sy = 0.f, sz = 0.f;
    for (int c = 0; c < C; ++c) {
        float xv = xc[c];
        float wt = W[c * Cout + j];
        float wb = W[(C + c) * Cout + j];
        sy = fmaf(xv, wt, sy);
        sz = fmaf(xv, wb - wt, sz);
    }
    y[(size_t)p * Cout + j] = sy;
    z[(size_t)p * Cout + j] = sz;
}

// ---------------- fused attention: one wave per point ----------------
template<int CO>
__global__ __launch_bounds__(256) void attn_kernel(const float* __restrict__ y,
                                                   const float* __restrict__ z,
                                                   const int* __restrict__ idx,
                                                   const float* __restrict__ a,
                                                   float* __restrict__ hout) {
    constexpr int NCH = CO / 64;
    constexpr int H   = CO / 4;
    int wv = threadIdx.x >> 6;
    int l  = threadIdx.x & 63;
    int p  = blockIdx.x * 4 + wv;             // b*N + n
    int b  = p >> 11;
    float hw[NCH][KNN], lg[NCH][KNN], zv[NCH], av[NCH];
#pragma unroll
    for (int q = 0; q < NCH; ++q) {
        int c = l + 64 * q;
        zv[q] = z[(size_t)p * CO + c];
        av[q] = a[(c & 3) * H + (c >> 2)];
    }
    const int* ip = idx + (size_t)p * KNN;
#pragma unroll
    for (int j = 0; j < KNN; ++j) {
        int m = ip[j];
        const float* yr = y + ((size_t)(b * NPTS) + m) * CO;
#pragma unroll
        for (int q = 0; q < NCH; ++q) {
            int c = l + 64 * q;
            float v = yr[c] + zv[q];
            hw[q][j] = v;
            float tt = v > 0.f ? v : v * SLOPE;
            float part = tt * av[q];
            part += __shfl_xor(part, 1);
            part += __shfl_xor(part, 2);
            lg[q][j] = part;                  // all 4 lanes of head group hold logit
        }
    }
#pragma unroll
    for (int q = 0; q < NCH; ++q) {
        float mx = -FLT_MAX;
#pragma unroll
        for (int j = 0; j < KNN; ++j) mx = fmaxf(mx, lg[q][j]);
        float s = 0.f;
#pragma unroll
        for (int j = 0; j < KNN; ++j) { float e = expf(lg[q][j] - mx); lg[q][j] = e; s += e; }
        float inv = 1.f / s;
        float o = 0.f;
#pragma unroll
        for (int j = 0; j < KNN; ++j) o = fmaf(lg[q][j] * inv, hw[q][j], o);
        o = o > 0.f ? o : o * SLOPE;
        int c = l + 64 * q;
        hout[(size_t)p * CO + c] = o;         // (B,N,C) layout, coalesced
    }
}

// ---------------- BN stats, deterministic two-stage ----------------
__global__ void bnstatA_kernel(const float* __restrict__ h, float* __restrict__ part, int CO) {
    __shared__ float s1[256], s2[256];
    int g = blockIdx.x, t = threadIdx.x;
    int c = t & (CO - 1), sub = t / CO;
    int nsub = 256 / CO;
    const int ppb = BN / 64;                  // 256 points per block
    float a1 = 0.f, a2 = 0.f;
    for (int i = 0; i < ppb / nsub; ++i) {
        int p = g * ppb + sub + i * nsub;
        float v = h[(size_t)p * CO + c];
        a1 += v; a2 = fmaf(v, v, a2);
    }
    s1[t] = a1; s2[t] = a2;
    __syncthreads();
    if (sub == 0) {
        for (int k = 1; k < nsub; ++k) { a1 += s1[k * CO + c]; a2 += s2[k * CO + c]; }
        part[(size_t)g * CO + c]        = a1;
        part[(size_t)(64 + g) * CO + c] = a2;
    }
}

__global__ void bnstatB_kernel(const float* __restrict__ part, float* __restrict__ mu,
                               float* __restrict__ rstd, int CO) {
    int c = threadIdx.x;
    float s1 = 0.f, s2 = 0.f;
    for (int g = 0; g < 64; ++g) { s1 += part[(size_t)g * CO + c]; s2 += part[(size_t)(64 + g) * CO + c]; }
    float m   = s1 / (float)BN;
    float var = s2 / (float)BN - m * m;
    mu[c]   = m;
    rstd[c] = 1.f / sqrtf(var + BNEPS);
}

// ---------------- BN apply + leaky + transpose to (B,C,N) ----------------
template<int CO>
__global__ __launch_bounds__(256) void bnapply_kernel(const float* __restrict__ h,
                                                      const float* __restrict__ mu,
                                                      const float* __restrict__ rstd,
                                                      const float* __restrict__ gamma,
                                                      const float* __restrict__ beta,
                                                      float* __restrict__ xout) {
    __shared__ float tile[64][CO + 1];
    int g  = blockIdx.x;
    int p0 = g * 64;
    int b  = p0 >> 11, n0 = p0 & (NPTS - 1);
    int t  = threadIdx.x;
    for (int fi = t; fi < 64 * CO; fi += 256) {
        int pt = fi / CO, c = fi % CO;
        tile[pt][c] = h[(size_t)(p0 + pt) * CO + c];
    }
    __syncthreads();
    for (int fi = t; fi < 64 * CO; fi += 256) {
        int c = fi >> 6, nn = fi & 63;
        float v = tile[nn][c];
        v = (v - mu[c]) * rstd[c] * gamma[c] + beta[c];
        v = v > 0.f ? v : v * SLOPE;
        xout[((size_t)b * CO + c) * NPTS + n0 + nn] = v;
    }
}

// ---------------- host ----------------
static void run_layer(const float* xin, const float* W, const float* a,
                      const float* gm, const float* bt, float* xout, int C, int CO,
                      float* xx, int* idx, float* y, float* z, float* h,
                      float* part, float* mu, float* rstd, hipStream_t stream) {
    xx_kernel<<<BN / 256, 256, 0, stream>>>(xin, xx, C);
    knn_kernel<<<BN, 256, 0, stream>>>(xin, xx, idx, C);
    proj_kernel<<<BN, CO, 0, stream>>>(xin, W, y, z, C, CO);
    if (CO == 64)
        attn_kernel<64><<<BN / 4, 256, 0, stream>>>(y, z, idx, a, h);
    else
        attn_kernel<128><<<BN / 4, 256, 0, stream>>>(y, z, idx, a, h);
    bnstatA_kernel<<<64, 256, 0, stream>>>(h, part, CO);
    bnstatB_kernel<<<1, CO, 0, stream>>>(part, mu, rstd, CO);
    if (CO == 64)
        bnapply_kernel<64><<<BN / 64, 256, 0, stream>>>(h, mu, rstd, gm, bt, xout);
    else
        bnapply_kernel<128><<<BN / 64, 256, 0, stream>>>(h, mu, rstd, gm, bt, xout);
}

extern "C" void kernel_launch(void* const* d_in, const int* in_sizes, int n_in,
                              void* d_out, int out_size, void* d_ws, size_t ws_size,
                              hipStream_t stream) {
    const float* x  = (const float*)d_in[0];
    const float* W[3]  = {(const float*)d_in[1], (const float*)d_in[5], (const float*)d_in[9]};
    const float* a[3]  = {(const float*)d_in[2], (const float*)d_in[6], (const float*)d_in[10]};
    const float* gm[3] = {(const float*)d_in[3], (const float*)d_in[7], (const float*)d_in[11]};
    const float* bt[3] = {(const float*)d_in[4], (const float*)d_in[8], (const float*)d_in[12]};

    char* base = (char*)d_ws;
    size_t off = 0;
    auto carve = [&](size_t bytes) -> void* {
        void* r = base + off;
        off = (off + bytes + 255) & ~(size_t)255;
        return r;
    };
    float* xx   = (float*)carve((size_t)BN * sizeof(float));
    int*   idx  = (int*)  carve((size_t)BN * KNN * sizeof(int));
    float* y    = (float*)carve((size_t)BN * 128 * sizeof(float));
    float* z    = (float*)carve((size_t)BN * 128 * sizeof(float));
    float* h    = (float*)carve((size_t)BN * 128 * sizeof(float));
    float* part = (float*)carve((size_t)128 * 128 * sizeof(float));
    float* mu   = (float*)carve(128 * sizeof(float));
    float* rstd = (float*)carve(128 * sizeof(float));
    float* x1   = (float*)carve((size_t)BATCH * 64 * NPTS * sizeof(float));
    float* x2   = (float*)carve((size_t)BATCH * 64 * NPTS * sizeof(float));
    float* out  = (float*)d_out;

    run_layer(x,  W[0], a[0], gm[0], bt[0], x1,  3,  64, xx, idx, y, z, h, part, mu, rstd, stream);
    run_layer(x1, W[1], a[1], gm[1], bt[1], x2,  64, 64, xx, idx, y, z, h, part, mu, rstd, stream);
    run_layer(x2, W[2], a[2], gm[2], bt[2], out, 64, 128, xx, idx, y, z, h, part, mu, rstd, stream);
}

// Round 2
// 765.486 us; speedup vs baseline: 1.7245x; 1.7245x over previous
//
#include <hip/hip_runtime.h>
#include <float.h>
#include <math.h>

#define BATCH 8
#define NPTS  2048
#define KNN   20
#define BN    (BATCH*NPTS)
#define SLOPE 0.2f
#define BNEPS 1e-5f

__device__ __forceinline__ float f4c(const float4& v, int cc) {
    return cc == 0 ? v.x : cc == 1 ? v.y : cc == 2 ? v.z : v.w;
}

// ---------------- xx: per-point squared norm ----------------
__global__ void xx_kernel(const float* __restrict__ x, float* __restrict__ xx, int C) {
    int p = blockIdx.x * 256 + threadIdx.x;           // p in [0, BN)
    int b = p >> 11, n = p & (NPTS - 1);
    const float* xb = x + (size_t)b * C * NPTS;
    float s = 0.f;
    for (int c = 0; c < C; ++c) { float v = xb[(size_t)c * NPTS + n]; s = fmaf(v, v, s); }
    xx[p] = s;
}

// ---------------- fused tiled kNN: 32 rows/block, streaming top-20 ----------------
template<int C>
__global__ __launch_bounds__(256) void knn2_kernel(const float* __restrict__ x,
                                                   const float* __restrict__ xx,
                                                   int* __restrict__ idx) {
    constexpr int ROWS = 32, CHUNK = 128, G = 8, M = CHUNK / G;   // M=16
    constexpr int NCH  = NPTS / CHUNK;                            // 16
    constexpr int XRS  = (C + 4) & ~3;                            // padded row stride (16B-aligned)
    constexpr int XCR  = (C > 4) ? C : 4;

    __shared__ __align__(16) float xr[ROWS][XRS];
    __shared__ float xxr_s[ROWS];
    __shared__ float xxc_s[CHUNK];
    __shared__ float dt[ROWS][CHUNK + 1];
    union UU {
        float xc[XCR][CHUNK];
        struct { float v[G][KNN][ROWS]; int i[G][KNN][ROWS]; } L;
    };
    __shared__ __align__(16) UU u;

    int t  = threadIdx.x;
    int b  = blockIdx.x >> 6;                 // NPTS/ROWS = 64 tiles per batch
    int r0 = (blockIdx.x & 63) * ROWS;
    const float* xb = x + (size_t)b * C * NPTS;

    // stage row features + row norms
    for (int f = t; f < ROWS * C; f += 256) {
        int r = f & (ROWS - 1), c = f >> 5;
        xr[r][c] = xb[(size_t)c * NPTS + r0 + r];
    }
    if (t < ROWS) xxr_s[t] = xx[b * NPTS + r0 + t];

    float lv[KNN]; int li[KNN];
#pragma unroll
    for (int s = 0; s < KNN; ++s) { lv[s] = FLT_MAX; li[s] = 0x7fffffff; }

    int ty = t >> 5, tx = t & 31;             // compute roles: row-quad ty, col-quad tx
                                              // selection roles: row = tx, group = ty

    for (int ch = 0; ch < NCH; ++ch) {
        int j0 = ch * CHUNK;
        __syncthreads();                      // xc reuse fence (vs prev compute reads)
        for (int f = t; f < C * CHUNK; f += 256) {
            int c = f >> 7, j = f & (CHUNK - 1);
            u.xc[c][j] = xb[(size_t)c * NPTS + j0 + j];
        }
        if (t < CHUNK) xxc_s[t] = xx[b * NPTS + j0 + t];
        __syncthreads();

        float acc[4][4];
#pragma unroll
        for (int i = 0; i < 4; ++i)
#pragma unroll
            for (int jj = 0; jj < 4; ++jj) acc[i][jj] = 0.f;

        if constexpr (C >= 4) {
            for (int c4 = 0; c4 < C; c4 += 4) {
                float4 rv4[4];
#pragma unroll
                for (int i = 0; i < 4; ++i)
                    rv4[i] = *(const float4*)&xr[ty * 4 + i][c4];
#pragma unroll
                for (int cc = 0; cc < 4; ++cc) {
                    float4 cv = *(const float4*)&u.xc[c4 + cc][tx * 4];
#pragma unroll
                    for (int i = 0; i < 4; ++i) {
                        float rv = f4c(rv4[i], cc);
                        acc[i][0] = fmaf(rv, cv.x, acc[i][0]);
                        acc[i][1] = fmaf(rv, cv.y, acc[i][1]);
                        acc[i][2] = fmaf(rv, cv.z, acc[i][2]);
                        acc[i][3] = fmaf(rv, cv.w, acc[i][3]);
                    }
                }
            }
        } else {
#pragma unroll
            for (int c = 0; c < C; ++c) {
                float4 cv = *(const float4*)&u.xc[c][tx * 4];
#pragma unroll
                for (int i = 0; i < 4; ++i) {
                    float rv = xr[ty * 4 + i][c];
                    acc[i][0] = fmaf(rv, cv.x, acc[i][0]);
                    acc[i][1] = fmaf(rv, cv.y, acc[i][1]);
                    acc[i][2] = fmaf(rv, cv.z, acc[i][2]);
                    acc[i][3] = fmaf(rv, cv.w, acc[i][3]);
                }
            }
        }

#pragma unroll
        for (int i = 0; i < 4; ++i) {
            float xxri = xxr_s[ty * 4 + i];
#pragma unroll
            for (int jj = 0; jj < 4; ++jj)
                dt[ty * 4 + i][tx * 4 + jj] = xxri - 2.f * acc[i][jj] + xxc_s[tx * 4 + jj];
        }
        __syncthreads();

        // streaming top-20: thread (row=tx, group=ty) scans 16 contiguous cols
        {
            int r = tx, g = ty;
#pragma unroll
            for (int m = 0; m < M; ++m) {
                int j = g * M + m;
                float v = dt[r][j];
                if (v < lv[KNN - 1]) {
                    lv[KNN - 1] = v; li[KNN - 1] = j0 + j;
#pragma unroll
                    for (int s = KNN - 1; s > 0; --s) {
                        if (lv[s] < lv[s - 1]) {
                            float tv = lv[s]; lv[s] = lv[s - 1]; lv[s - 1] = tv;
                            int   ti = li[s]; li[s] = li[s - 1]; li[s - 1] = ti;
                        }
                    }
                }
            }
        }
    }

    __syncthreads();
    {
        int r = tx, g = ty;
#pragma unroll
        for (int s = 0; s < KNN; ++s) { u.L.v[g][s][r] = lv[s]; u.L.i[g][s][r] = li[s]; }
    }
    __syncthreads();

    if (t < ROWS) {
        int r = t;
        int p[G]; float hv[G]; int hi[G];
#pragma unroll
        for (int g = 0; g < G; ++g) { p[g] = 0; hv[g] = u.L.v[g][0][r]; hi[g] = u.L.i[g][0][r]; }
        int* op = idx + (size_t)(b * NPTS + r0 + r) * KNN;
        for (int o = 0; o < KNN; ++o) {
            float bv = hv[0]; int bi = hi[0]; int bg = 0;
#pragma unroll
            for (int g = 1; g < G; ++g)
                if (hv[g] < bv || (hv[g] == bv && hi[g] < bi)) { bv = hv[g]; bi = hi[g]; bg = g; }
            op[o] = bi;
#pragma unroll
            for (int g = 0; g < G; ++g)
                if (bg == g) {
                    ++p[g];
                    bool ok = p[g] < KNN;
                    int pp = ok ? p[g] : KNN - 1;
                    float nv = u.L.v[g][pp][r]; int ni = u.L.i[g][pp][r];
                    hv[g] = ok ? nv : FLT_MAX;
                    hi[g] = ok ? ni : 0x7fffffff;
                }
        }
    }
}

// ---------------- projection: y = x@Wtop, z = x@(Wbot-Wtop) ----------------
__global__ void proj_kernel(const float* __restrict__ x, const float* __restrict__ W,
                            float* __restrict__ y, float* __restrict__ z, int C, int Cout) {
    int p = blockIdx.x;
    int b = p >> 11, n = p & (NPTS - 1);
    int j = threadIdx.x;                      // j < Cout
    __shared__ float xc[64];
    if (j < C) xc[j] = x[(size_t)b * C * NPTS + (size_t)j * NPTS + n];
    __syncthreads();
    float sy = 0.f, sz = 0.f;
    for (int c = 0; c < C; ++c) {
        float xv = xc[c];
        float wt = W[c * Cout + j];
        float wb = W[(C + c) * Cout + j];
        sy = fmaf(xv, wt, sy);
        sz = fmaf(xv, wb - wt, sz);
    }
    y[(size_t)p * Cout + j] = sy;
    z[(size_t)p * Cout + j] = sz;
}

// ---------------- fused attention: one wave per point ----------------
template<int CO>
__global__ __launch_bounds__(256) void attn_kernel(const float* __restrict__ y,
                                                   const float* __restrict__ z,
                                                   const int* __restrict__ idx,
                                                   const float* __restrict__ a,
                                                   float* __restrict__ hout) {
    constexpr int NCH = CO / 64;
    constexpr int H   = CO / 4;
    int wv = threadIdx.x >> 6;
    int l  = threadIdx.x & 63;
    int p  = blockIdx.x * 4 + wv;             // b*N + n
    int b  = p >> 11;
    float hw[NCH][KNN], lg[NCH][KNN], zv[NCH], av[NCH];
#pragma unroll
    for (int q = 0; q < NCH; ++q) {
        int c = l + 64 * q;
        zv[q] = z[(size_t)p * CO + c];
        av[q] = a[(c & 3) * H + (c >> 2)];
    }
    const int* ip = idx + (size_t)p * KNN;
#pragma unroll
    for (int j = 0; j < KNN; ++j) {
        int m = ip[j];
        const float* yr = y + ((size_t)(b * NPTS) + m) * CO;
#pragma unroll
        for (int q = 0; q < NCH; ++q) {
            int c = l + 64 * q;
            float v = yr[c] + zv[q];
            hw[q][j] = v;
            float tt = v > 0.f ? v : v * SLOPE;
            float part = tt * av[q];
            part += __shfl_xor(part, 1);
            part += __shfl_xor(part, 2);
            lg[q][j] = part;
        }
    }
#pragma unroll
    for (int q = 0; q < NCH; ++q) {
        float mx = -FLT_MAX;
#pragma unroll
        for (int j = 0; j < KNN; ++j) mx = fmaxf(mx, lg[q][j]);
        float s = 0.f;
#pragma unroll
        for (int j = 0; j < KNN; ++j) { float e = expf(lg[q][j] - mx); lg[q][j] = e; s += e; }
        float inv = 1.f / s;
        float o = 0.f;
#pragma unroll
        for (int j = 0; j < KNN; ++j) o = fmaf(lg[q][j] * inv, hw[q][j], o);
        o = o > 0.f ? o : o * SLOPE;
        int c = l + 64 * q;
        hout[(size_t)p * CO + c] = o;
    }
}

// ---------------- BN stats, deterministic two-stage ----------------
__global__ void bnstatA_kernel(const float* __restrict__ h, float* __restrict__ part, int CO) {
    __shared__ float s1[256], s2[256];
    int g = blockIdx.x, t = threadIdx.x;
    int c = t & (CO - 1), sub = t / CO;
    int nsub = 256 / CO;
    const int ppb = BN / 64;                  // 256 points per block
    float a1 = 0.f, a2 = 0.f;
    for (int i = 0; i < ppb / nsub; ++i) {
        int p = g * ppb + sub + i * nsub;
        float v = h[(size_t)p * CO + c];
        a1 += v; a2 = fmaf(v, v, a2);
    }
    s1[t] = a1; s2[t] = a2;
    __syncthreads();
    if (sub == 0) {
        for (int k = 1; k < nsub; ++k) { a1 += s1[k * CO + c]; a2 += s2[k * CO + c]; }
        part[(size_t)g * CO + c]        = a1;
        part[(size_t)(64 + g) * CO + c] = a2;
    }
}

__global__ void bnstatB_kernel(const float* __restrict__ part, float* __restrict__ mu,
                               float* __restrict__ rstd, int CO) {
    int c = threadIdx.x;
    float s1 = 0.f, s2 = 0.f;
    for (int g = 0; g < 64; ++g) { s1 += part[(size_t)g * CO + c]; s2 += part[(size_t)(64 + g) * CO + c]; }
    float m   = s1 / (float)BN;
    float var = s2 / (float)BN - m * m;
    mu[c]   = m;
    rstd[c] = 1.f / sqrtf(var + BNEPS);
}

// ---------------- BN apply + leaky + transpose to (B,C,N) ----------------
template<int CO>
__global__ __launch_bounds__(256) void bnapply_kernel(const float* __restrict__ h,
                                                      const float* __restrict__ mu,
                                                      const float* __restrict__ rstd,
                                                      const float* __restrict__ gamma,
                                                      const float* __restrict__ beta,
                                                      float* __restrict__ xout) {
    __shared__ float tile[64][CO + 1];
    int g  = blockIdx.x;
    int p0 = g * 64;
    int b  = p0 >> 11, n0 = p0 & (NPTS - 1);
    int t  = threadIdx.x;
    for (int fi = t; fi < 64 * CO; fi += 256) {
        int pt = fi / CO, c = fi % CO;
        tile[pt][c] = h[(size_t)(p0 + pt) * CO + c];
    }
    __syncthreads();
    for (int fi = t; fi < 64 * CO; fi += 256) {
        int c = fi >> 6, nn = fi & 63;
        float v = tile[nn][c];
        v = (v - mu[c]) * rstd[c] * gamma[c] + beta[c];
        v = v > 0.f ? v : v * SLOPE;
        xout[((size_t)b * CO + c) * NPTS + n0 + nn] = v;
    }
}

// ---------------- host ----------------
static void run_layer(const float* xin, const float* W, const float* a,
                      const float* gm, const float* bt, float* xout, int C, int CO,
                      float* xx, int* idx, float* y, float* z, float* h,
                      float* part, float* mu, float* rstd, hipStream_t stream) {
    xx_kernel<<<BN / 256, 256, 0, stream>>>(xin, xx, C);
    if (C == 3)
        knn2_kernel<3><<<BATCH * (NPTS / 32), 256, 0, stream>>>(xin, xx, idx);
    else
        knn2_kernel<64><<<BATCH * (NPTS / 32), 256, 0, stream>>>(xin, xx, idx);
    proj_kernel<<<BN, CO, 0, stream>>>(xin, W, y, z, C, CO);
    if (CO == 64)
        attn_kernel<64><<<BN / 4, 256, 0, stream>>>(y, z, idx, a, h);
    else
        attn_kernel<128><<<BN / 4, 256, 0, stream>>>(y, z, idx, a, h);
    bnstatA_kernel<<<64, 256, 0, stream>>>(h, part, CO);
    bnstatB_kernel<<<1, CO, 0, stream>>>(part, mu, rstd, CO);
    if (CO == 64)
        bnapply_kernel<64><<<BN / 64, 256, 0, stream>>>(h, mu, rstd, gm, bt, xout);
    else
        bnapply_kernel<128><<<BN / 64, 256, 0, stream>>>(h, mu, rstd, gm, bt, xout);
}

extern "C" void kernel_launch(void* const* d_in, const int* in_sizes, int n_in,
                              void* d_out, int out_size, void* d_ws, size_t ws_size,
                              hipStream_t stream) {
    const float* x  = (const float*)d_in[0];
    const float* W[3]  = {(const float*)d_in[1], (const float*)d_in[5], (const float*)d_in[9]};
    const float* a[3]  = {(const float*)d_in[2], (const float*)d_in[6], (const float*)d_in[10]};
    const float* gm[3] = {(const float*)d_in[3], (const float*)d_in[7], (const float*)d_in[11]};
    const float* bt[3] = {(const float*)d_in[4], (const float*)d_in[8], (const float*)d_in[12]};

    char* base = (char*)d_ws;
    size_t off = 0;
    auto carve = [&](size_t bytes) -> void* {
        void* r = base + off;
        off = (off + bytes + 255) & ~(size_t)255;
        return r;
    };
    float* xx   = (float*)carve((size_t)BN * sizeof(float));
    int*   idx  = (int*)  carve((size_t)BN * KNN * sizeof(int));
    float* y    = (float*)carve((size_t)BN * 128 * sizeof(float));
    float* z    = (float*)carve((size_t)BN * 128 * sizeof(float));
    float* h    = (float*)carve((size_t)BN * 128 * sizeof(float));
    float* part = (float*)carve((size_t)128 * 128 * sizeof(float));
    float* mu   = (float*)carve(128 * sizeof(float));
    float* rstd = (float*)carve(128 * sizeof(float));
    float* x1   = (float*)carve((size_t)BATCH * 64 * NPTS * sizeof(float));
    float* x2   = (float*)carve((size_t)BATCH * 64 * NPTS * sizeof(float));
    float* out  = (float*)d_out;

    run_layer(x,  W[0], a[0], gm[0], bt[0], x1,  3,  64, xx, idx, y, z, h, part, mu, rstd, stream);
    run_layer(x1, W[1], a[1], gm[1], bt[1], x2,  64, 64, xx, idx, y, z, h, part, mu, rstd, stream);
    run_layer(x2, W[2], a[2], gm[2], bt[2], out, 64, 128, xx, idx, y, z, h, part, mu, rstd, stream);
}